// Round 1
// baseline (27184.070 us; speedup 1.0000x reference)
//
#include <hip/hip_runtime.h>

// GPT-2 circuit-decomposition model, f32 reference-faithful implementation.
// Constants
#define SS 128      // sequence
#define DD 768      // hidden
#define HH 12       // heads
#define DHD 64      // head dim
#define FF 3072     // mlp dim
#define VV 50257    // vocab
#define NCC 29      // circuits per layer
#define LL 12       // layers
#define SD (SS*DD)      // 98304
#define SF (SS*FF)      // 393216
#define SDH (SS*DHD)    // 8192

// ---------------- mask pre-pack: lmask[i][t] bit j = rm[(i*29+j)][t], t = l*29+c
__global__ void k_masks(const int* __restrict__ rm, unsigned* __restrict__ lmask) {
    int idx = blockIdx.x * 64 + threadIdx.x;
    if (idx >= LL * (LL * NCC)) return;
    int i = idx / (LL * NCC), t = idx % (LL * NCC);
    unsigned m = 0;
    for (int j = 0; j < 26; j++)
        m |= (unsigned)(rm[(size_t)(i * NCC + j) * (LL * NCC) + t] & 1) << j;
    lmask[idx] = m;
}

// ---------------- embedding: h = wte[ids] + wpe[:S]
__global__ void k_embed(const int* __restrict__ ids, const float* __restrict__ wte,
                        const float* __restrict__ wpe, float* __restrict__ h) {
    int sd = blockIdx.x * 256 + threadIdx.x;
    if (sd >= SD) return;
    int s = sd / DD, d = sd % DD;
    h[sd] = wte[(size_t)ids[s] * DD + d] + wpe[sd];
}

// ---------------- checks: 26 gated record-sums, records read exactly once
__global__ __launch_bounds__(256) void k_check(
    const float* __restrict__ records, const unsigned* __restrict__ lmask,
    const float* __restrict__ h, float* __restrict__ rec0, float* __restrict__ x2,
    float* __restrict__ x3, float* __restrict__ x4, int layer) {
    int sd = blockIdx.x * 256 + threadIdx.x;
    if (sd >= SD) return;
    float acc[26];
#pragma unroll
    for (int j = 0; j < 26; j++) acc[j] = 0.f;
    const unsigned* lm = lmask + layer * (LL * NCC);
    int T = layer * NCC;
    for (int t = 0; t < T; t++) {
        float r = records[(size_t)t * SD + sd];
        unsigned m = lm[t];
#pragma unroll
        for (int j = 0; j < 26; j++)
            if (m & (1u << j)) acc[j] += r;
    }
    float hv = h[sd];
    rec0[sd] = hv - acc[0];
#pragma unroll
    for (int j = 0; j < 12; j++) x2[(size_t)j * SD + sd] = hv - acc[1 + j];
    x3[sd] = hv - acc[13];
#pragma unroll
    for (int j = 0; j < 12; j++) x4[(size_t)j * SD + sd] = hv - acc[14 + j];
}

// ---------------- LayerNorm, one wave (64 lanes) per 768-row; in==out allowed
__global__ __launch_bounds__(64) void k_ln(const float* __restrict__ in, float* __restrict__ out,
                                           const float* __restrict__ g, const float* __restrict__ b,
                                           int R) {
    int row = blockIdx.x;
    if (row >= R) return;
    int lane = threadIdx.x;
    const float* x = in + (size_t)row * DD;
    float vals[12];
    float s = 0.f;
#pragma unroll
    for (int i = 0; i < 12; i++) { vals[i] = x[lane + 64 * i]; s += vals[i]; }
#pragma unroll
    for (int m = 32; m >= 1; m >>= 1) s += __shfl_xor(s, m, 64);
    float mean = s * (1.f / DD);
    float vs = 0.f;
#pragma unroll
    for (int i = 0; i < 12; i++) { float d = vals[i] - mean; vs += d * d; }
#pragma unroll
    for (int m = 32; m >= 1; m >>= 1) vs += __shfl_xor(vs, m, 64);
    float rstd = rsqrtf(vs * (1.f / DD) + 1e-5f);
    float* o = out + (size_t)row * DD;
#pragma unroll
    for (int i = 0; i < 12; i++) {
        int d = lane + 64 * i;
        o[d] = (vals[i] - mean) * rstd * g[d] + b[d];
    }
}

// ---------------- generic NN GEMM: C[b] = A[b] @ B[b] (+bias[b]), row-major
// 64x64 tile, BK=16, 256 threads, 4x4 per thread. A staged transposed in LDS
// so both fragment reads are float4.
__global__ __launch_bounds__(256) void k_gemm(
    const float* __restrict__ A, const float* __restrict__ B,
    const float* __restrict__ bias, float* __restrict__ C,
    int M, int N, int K, int lda, int ldb, int ldc,
    long long sA, long long sB, long long sC, long long sBias) {
    __shared__ float As[16][68];  // [k][m]
    __shared__ float Bs[16][68];  // [k][n]
    int bz = blockIdx.z;
    const float* Ab = A + bz * sA;
    const float* Bb = B + bz * sB;
    float* Cb = C + bz * sC;
    int n0 = blockIdx.x * 64, m0 = blockIdx.y * 64;
    int tid = threadIdx.x;
    int tx = tid & 15, ty = tid >> 4;
    int ar = tid >> 4, ac = tid & 15;   // A-load: 16 rows x 16 k per pass
    int br = tid >> 6, bc = tid & 63;   // B-load: 4 k x 64 n per pass
    float acc[4][4];
#pragma unroll
    for (int i = 0; i < 4; i++)
#pragma unroll
        for (int j = 0; j < 4; j++) acc[i][j] = 0.f;
    for (int k0 = 0; k0 < K; k0 += 16) {
#pragma unroll
        for (int i = 0; i < 4; i++) {
            int ml = ar + 16 * i;
            int m = m0 + ml;
            As[ac][ml] = (m < M) ? Ab[(size_t)m * lda + k0 + ac] : 0.f;
        }
#pragma unroll
        for (int i = 0; i < 4; i++) {
            int n = n0 + bc;
            Bs[br + 4 * i][bc] = (n < N) ? Bb[(size_t)(k0 + br + 4 * i) * ldb + n] : 0.f;
        }
        __syncthreads();
#pragma unroll
        for (int kk = 0; kk < 16; kk++) {
            float4 av = *(const float4*)&As[kk][ty * 4];
            float4 bv = *(const float4*)&Bs[kk][tx * 4];
            float a4[4] = {av.x, av.y, av.z, av.w};
            float b4[4] = {bv.x, bv.y, bv.z, bv.w};
#pragma unroll
            for (int i = 0; i < 4; i++)
#pragma unroll
                for (int j = 0; j < 4; j++) acc[i][j] += a4[i] * b4[j];
        }
        __syncthreads();
    }
#pragma unroll
    for (int i = 0; i < 4; i++) {
        int m = m0 + ty * 4 + i;
        if (m >= M) continue;
#pragma unroll
        for (int j = 0; j < 4; j++) {
            int n = n0 + tx * 4 + j;
            if (n >= N) continue;
            float v = acc[i][j];
            if (bias) v += bias[bz * sBias + n];
            Cb[(size_t)m * ldc + n] = v;
        }
    }
}

// ---------------- NT GEMM for logits: C[m,n] = sum_k A[m,k] * W[n,k]
__global__ __launch_bounds__(256) void k_gemm_nt(
    const float* __restrict__ A, const float* __restrict__ W, float* __restrict__ C,
    int M, int N, int K) {
    __shared__ float As[16][68];  // [k][m]
    __shared__ float Ws[16][68];  // [k][n]
    int n0 = blockIdx.x * 64, m0 = blockIdx.y * 64;
    int tid = threadIdx.x;
    int tx = tid & 15, ty = tid >> 4;
    int ar = tid >> 4, ac = tid & 15;
    float acc[4][4];
#pragma unroll
    for (int i = 0; i < 4; i++)
#pragma unroll
        for (int j = 0; j < 4; j++) acc[i][j] = 0.f;
    for (int k0 = 0; k0 < K; k0 += 16) {
#pragma unroll
        for (int i = 0; i < 4; i++) {
            int ml = ar + 16 * i;
            int m = m0 + ml;
            As[ac][ml] = (m < M) ? A[(size_t)m * K + k0 + ac] : 0.f;
            int n = n0 + ml;
            Ws[ac][ml] = (n < N) ? W[(size_t)n * K + k0 + ac] : 0.f;
        }
        __syncthreads();
#pragma unroll
        for (int kk = 0; kk < 16; kk++) {
            float4 av = *(const float4*)&As[kk][ty * 4];
            float4 bv = *(const float4*)&Ws[kk][tx * 4];
            float a4[4] = {av.x, av.y, av.z, av.w};
            float b4[4] = {bv.x, bv.y, bv.z, bv.w};
#pragma unroll
            for (int i = 0; i < 4; i++)
#pragma unroll
                for (int j = 0; j < 4; j++) acc[i][j] += a4[i] * b4[j];
        }
        __syncthreads();
    }
#pragma unroll
    for (int i = 0; i < 4; i++) {
        int m = m0 + ty * 4 + i;
        if (m >= M) continue;
#pragma unroll
        for (int j = 0; j < 4; j++) {
            int n = n0 + tx * 4 + j;
            if (n >= N) continue;
            C[(size_t)m * N + n] = acc[i][j];
        }
    }
}

// ---------------- fused causal attention (scores+softmax+ctx) per head
// grid (S/16, H), block 256. K then V staged in same 32KB LDS region.
__global__ __launch_bounds__(256) void k_attn(const float* __restrict__ q,
                                              const float* __restrict__ k,
                                              const float* __restrict__ v,
                                              float* __restrict__ ctx) {
    __shared__ float kv[SS * DHD];   // 32 KB
    __shared__ float qs[16][DHD];    // 4 KB
    __shared__ float sc[16][130];    // 8.1 KB
    int h = blockIdx.y, s0 = blockIdx.x * 16;
    size_t hb = (size_t)h * SDH;
    int tid = threadIdx.x;
    for (int idx = tid; idx < SS * DHD; idx += 256) kv[idx] = k[hb + idx];
    for (int idx = tid; idx < 16 * DHD; idx += 256)
        qs[idx / DHD][idx % DHD] = q[hb + (size_t)s0 * DHD + idx];
    __syncthreads();
    int r = tid >> 4, tt = tid & 15;
    int s = s0 + r;
    float pl[8];
#pragma unroll
    for (int u = 0; u < 8; u++) {
        int t = tt + 16 * u;
        float dot;
        if (t <= s) {
            dot = 0.f;
            for (int d = 0; d < DHD; d++) dot += qs[r][d] * kv[t * DHD + d];
            dot *= 0.125f;  // 1/sqrt(64)
        } else {
            dot = -1e30f;
        }
        pl[u] = dot;
    }
    float mx = pl[0];
#pragma unroll
    for (int u = 1; u < 8; u++) mx = fmaxf(mx, pl[u]);
#pragma unroll
    for (int m = 1; m < 16; m <<= 1) mx = fmaxf(mx, __shfl_xor(mx, m, 16));
    float sum = 0.f;
#pragma unroll
    for (int u = 0; u < 8; u++) { pl[u] = __expf(pl[u] - mx); sum += pl[u]; }
#pragma unroll
    for (int m = 1; m < 16; m <<= 1) sum += __shfl_xor(sum, m, 16);
    float inv = 1.f / sum;
#pragma unroll
    for (int u = 0; u < 8; u++) sc[r][tt + 16 * u] = pl[u] * inv;
    __syncthreads();
    for (int idx = tid; idx < SS * DHD; idx += 256) kv[idx] = v[hb + idx];
    __syncthreads();
    int d = tid & 63, r0 = tid >> 6;
#pragma unroll
    for (int u = 0; u < 4; u++) {
        int rr = r0 + 4 * u;
        float a = 0.f;
        for (int t = 0; t < SS; t++) a += sc[rr][t] * kv[t * DHD + d];
        ctx[hb + (size_t)(s0 + rr) * DHD + d] = a;
    }
}

// ---------------- gelu (tanh approx, GPT-2 gelu_new), in place
__global__ void k_gelu(float* __restrict__ x, int n) {
    int i0 = blockIdx.x * blockDim.x + threadIdx.x;
    int stride = gridDim.x * blockDim.x;
    for (int idx = i0; idx < n; idx += stride) {
        float v = x[idx];
        float c = v + 0.044715f * v * v * v;
        x[idx] = 0.5f * v * (1.f + tanhf(0.7978845608028654f * c));
    }
}

// ---------------- residual = c1 + sum(head2) + proj_b ; also slots 27/28
__global__ void k_resid(const float* __restrict__ reci, const float* __restrict__ proj_b_i,
                        const float* __restrict__ mproj_b_i, float* __restrict__ resid,
                        float* __restrict__ slot27, float* __restrict__ slot28) {
    int sd = blockIdx.x * 256 + threadIdx.x;
    if (sd >= SD) return;
    int d = sd % DD;
    float a = reci[sd];
#pragma unroll
    for (int j = 1; j <= 12; j++) a += reci[(size_t)j * SD + sd];
    resid[sd] = a + proj_b_i[d];
    slot27[sd] = mproj_b_i[d];
    slot28[sd] = proj_b_i[d];
}

// ---------------- c5 = stream - c3 - sum(c4) ; h = resid + stream + mproj_b
__global__ void k_c5h(const float* __restrict__ reci, const float* __restrict__ strm,
                      const float* __restrict__ resid, const float* __restrict__ mproj_b_i,
                      float* __restrict__ slot26, float* __restrict__ h) {
    int sd = blockIdx.x * 256 + threadIdx.x;
    if (sd >= SD) return;
    int d = sd % DD;
    float s4 = 0.f;
#pragma unroll
    for (int j = 14; j <= 25; j++) s4 += reci[(size_t)j * SD + sd];
    float st = strm[sd];
    slot26[sd] = st - reci[(size_t)13 * SD + sd] - s4;
    h[sd] = resid[sd] + st + mproj_b_i[d];
}

extern "C" void kernel_launch(void* const* d_in, const int* in_sizes, int n_in,
                              void* d_out, int out_size, void* d_ws, size_t ws_size,
                              hipStream_t stream) {
    const int* ids = (const int*)d_in[0];
    const int* rm = (const int*)d_in[2];
    const float* wte = (const float*)d_in[3];
    const float* wpe = (const float*)d_in[4];
    const float* qkv_w = (const float*)d_in[5];
    const float* qkv_b = (const float*)d_in[6];
    const float* proj_w = (const float*)d_in[7];
    const float* proj_b = (const float*)d_in[8];
    const float* ln1_g = (const float*)d_in[9];
    const float* ln1_b = (const float*)d_in[10];
    const float* ln2_g = (const float*)d_in[11];
    const float* ln2_b = (const float*)d_in[12];
    const float* fc_w = (const float*)d_in[13];
    const float* fc_b = (const float*)d_in[14];
    const float* mproj_w = (const float*)d_in[15];
    const float* mproj_b = (const float*)d_in[16];
    const float* lnf_g = (const float*)d_in[17];
    const float* lnf_b = (const float*)d_in[18];
    float* out = (float*)d_out;

    // workspace layout (floats)
    float* ws = (float*)d_ws;
    size_t off = 0;
    float* records = ws + off; off += (size_t)LL * NCC * SD;  // 34,209,792
    float* x2   = ws + off; off += (size_t)HH * SD;           // 1,179,648
    float* x4   = ws + off; off += (size_t)HH * SD;
    float* lnh4 = ws + off; off += (size_t)HH * SD;
    float* hfc  = ws + off; off += (size_t)HH * SF;           // 4,718,592
    float* h    = ws + off; off += SD;
    float* x3   = ws + off; off += SD;
    float* resid= ws + off; off += SD;
    float* strm = ws + off; off += SD;
    float* lnres= ws + off; off += SD;
    float* qb   = ws + off; off += (size_t)HH * SDH;
    float* kb   = ws + off; off += (size_t)HH * SDH;
    float* vb   = ws + off; off += (size_t)HH * SDH;
    float* ctx  = ws + off; off += (size_t)HH * SDH;
    unsigned* lmask = (unsigned*)(ws + off);                  // 4176 u32

    k_masks<<<(LL * LL * NCC + 63) / 64, 64, 0, stream>>>(rm, lmask);
    k_embed<<<SD / 256, 256, 0, stream>>>(ids, wte, wpe, h);

    for (int i = 0; i < LL; i++) {
        float* reci = records + (size_t)i * NCC * SD;
        const float* l1g = ln1_g + i * DD; const float* l1b = ln1_b + i * DD;
        const float* l2g = ln2_g + i * DD; const float* l2b = ln2_b + i * DD;
        const float* fcw = fc_w + (size_t)i * DD * FF;
        const float* mpw = mproj_w + (size_t)i * FF * DD;

        k_check<<<SD / 256, 256, 0, stream>>>(records, lmask, h, reci, x2, x3, x4, i);

        // ---- circuit 2: per-head attention on x2
        k_ln<<<HH * SS, 64, 0, stream>>>(x2, x2, l1g, l1b, HH * SS);
        for (int p = 0; p < 3; p++) {
            float* dst = (p == 0) ? qb : ((p == 1) ? kb : vb);
            k_gemm<<<dim3(1, 2, 12), 256, 0, stream>>>(
                x2, qkv_w + (size_t)i * DD * 3 * DD + p * DD, qkv_b + (size_t)i * 3 * DD + p * DD,
                dst, SS, DHD, DD, DD, 3 * DD, DHD, SD, DHD, SDH, DHD);
        }
        k_attn<<<dim3(SS / 16, HH), 256, 0, stream>>>(qb, kb, vb, ctx);
        k_gemm<<<dim3(12, 2, 12), 256, 0, stream>>>(
            ctx, proj_w + (size_t)i * DD * DD, nullptr, reci + SD,
            SS, DD, DHD, DHD, DD, DD, SDH, (long long)DHD * DD, SD, 0);
        k_resid<<<SD / 256, 256, 0, stream>>>(reci, proj_b + i * DD, mproj_b + i * DD,
                                              resid, reci + (size_t)27 * SD, reci + (size_t)28 * SD);

        // ---- full MLP stream on residual (fc bias, no proj bias)
        k_ln<<<SS, 64, 0, stream>>>(resid, lnres, l2g, l2b, SS);
        k_gemm<<<dim3(48, 2, 1), 256, 0, stream>>>(lnres, fcw, fc_b + (size_t)i * FF, hfc,
                                                   SS, FF, DD, DD, FF, FF, 0, 0, 0, 0);
        k_gelu<<<512, 256, 0, stream>>>(hfc, SF);
        k_gemm<<<dim3(12, 2, 1), 256, 0, stream>>>(hfc, mpw, nullptr, strm,
                                                   SS, DD, FF, FF, DD, DD, 0, 0, 0, 0);

        // ---- circuit 3: bias-free MLP of double-LN'd x3
        k_ln<<<SS, 64, 0, stream>>>(x3, x3, l1g, l1b, SS);
        k_ln<<<SS, 64, 0, stream>>>(x3, x3, l2g, l2b, SS);
        k_gemm<<<dim3(48, 2, 1), 256, 0, stream>>>(x3, fcw, nullptr, hfc,
                                                   SS, FF, DD, DD, FF, FF, 0, 0, 0, 0);
        k_gelu<<<512, 256, 0, stream>>>(hfc, SF);
        k_gemm<<<dim3(12, 2, 1), 256, 0, stream>>>(hfc, mpw, nullptr, reci + (size_t)13 * SD,
                                                   SS, DD, FF, FF, DD, DD, 0, 0, 0, 0);

        // ---- circuit 4: per-head attention on x4 -> per-head MLP
        k_ln<<<HH * SS, 64, 0, stream>>>(x4, x4, l1g, l1b, HH * SS);
        for (int p = 0; p < 3; p++) {
            float* dst = (p == 0) ? qb : ((p == 1) ? kb : vb);
            k_gemm<<<dim3(1, 2, 12), 256, 0, stream>>>(
                x4, qkv_w + (size_t)i * DD * 3 * DD + p * DD, qkv_b + (size_t)i * 3 * DD + p * DD,
                dst, SS, DHD, DD, DD, 3 * DD, DHD, SD, DHD, SDH, DHD);
        }
        k_attn<<<dim3(SS / 16, HH), 256, 0, stream>>>(qb, kb, vb, ctx);
        k_gemm<<<dim3(12, 2, 12), 256, 0, stream>>>(
            ctx, proj_w + (size_t)i * DD * DD, nullptr, reci + (size_t)14 * SD,
            SS, DD, DHD, DHD, DD, DD, SDH, (long long)DHD * DD, SD, 0);
        k_ln<<<HH * SS, 64, 0, stream>>>(reci + (size_t)14 * SD, lnh4, l2g, l2b, HH * SS);
        k_gemm<<<dim3(48, 2, 12), 256, 0, stream>>>(lnh4, fcw, nullptr, hfc,
                                                    SS, FF, DD, DD, FF, FF, SD, 0, SF, 0);
        k_gelu<<<2048, 256, 0, stream>>>(hfc, HH * SF);
        k_gemm<<<dim3(12, 2, 12), 256, 0, stream>>>(hfc, mpw, nullptr, reci + (size_t)14 * SD,
                                                    SS, DD, FF, FF, DD, DD, SF, 0, SD, 0);

        // ---- c5, c6, new h
        k_c5h<<<SD / 256, 256, 0, stream>>>(reci, strm, resid, mproj_b + i * DD,
                                            reci + (size_t)26 * SD, h);
    }

    // final LN + logits = ln(h) @ wte^T
    k_ln<<<SS, 64, 0, stream>>>(h, lnres, lnf_g, lnf_b, SS);
    k_gemm_nt<<<dim3((VV + 63) / 64, 2), 256, 0, stream>>>(lnres, wte, out, SS, VV, DD);
}

// Round 2
// 3936.217 us; speedup vs baseline: 6.9061x; 6.9061x over previous
//
#include <hip/hip_runtime.h>

#define SS 128
#define DD 768
#define HH 12
#define DHD 64
#define FF 3072
#define VV 50257
#define NCC 29
#define LL 12
#define SD (SS*DD)      // 98304
#define SF (SS*FF)      // 393216

typedef unsigned short u16;
typedef __attribute__((ext_vector_type(8))) short short8;
typedef __attribute__((ext_vector_type(4))) float f32x4;

__device__ inline u16 f2bf(float f) {
    union { float f; unsigned u; } x; x.f = f;
    unsigned r = x.u + 0x7fffu + ((x.u >> 16) & 1u);
    return (u16)(r >> 16);
}

// ---------------- mask pre-pack
__global__ void k_masks(const int* __restrict__ rm, unsigned* __restrict__ lmask) {
    int idx = blockIdx.x * 64 + threadIdx.x;
    if (idx >= LL * (LL * NCC)) return;
    int i = idx / (LL * NCC), t = idx % (LL * NCC);
    unsigned m = 0;
    for (int j = 0; j < 26; j++)
        m |= (unsigned)(rm[(size_t)(i * NCC + j) * (LL * NCC) + t] & 1) << j;
    lmask[idx] = m;
}

// ---------------- embedding
__global__ void k_embed(const int* __restrict__ ids, const float* __restrict__ wte,
                        const float* __restrict__ wpe, float* __restrict__ h) {
    int sd = blockIdx.x * 256 + threadIdx.x;
    if (sd >= SD) return;
    int s = sd / DD, d = sd % DD;
    h[sd] = wte[(size_t)ids[s] * DD + d] + wpe[sd];
}

// ---------------- f32 -> bf16 elementwise (wte)
__global__ void k_cvt(const float* __restrict__ in, u16* __restrict__ out, int n4) {
    int i = blockIdx.x * 256 + threadIdx.x;
    if (i >= n4) return;
    float4 v = *(const float4*)(in + (size_t)i * 4);
    u16* o = out + (size_t)i * 4;
    o[0] = f2bf(v.x); o[1] = f2bf(v.y); o[2] = f2bf(v.z); o[3] = f2bf(v.w);
}

// ---------------- qkv bias pack: [L][3*D] -> [L][12 heads][192]
__global__ void k_qkvb(const float* __restrict__ qkv_b, float* __restrict__ qkvbp) {
    int idx = blockIdx.x * 256 + threadIdx.x;
    if (idx >= LL * 3 * DD) return;
    int l = idx / (3 * DD), r = idx % (3 * DD);
    int p = r / DD, rem = r % DD, h = rem / DHD, j = rem % DHD;
    qkvbp[(size_t)l * 3 * DD + h * 192 + p * DHD + j] = qkv_b[idx];
}

// ---------------- weight transpose-convert: W[K][N] f32 -> WT[N][K] bf16
// remap=1: qkv head-interleave (out row block h*3+p <- in col block p*12+h)
__global__ __launch_bounds__(256) void k_wt(const float* __restrict__ W, u16* __restrict__ WT,
                                            int K, int N, int remap) {
    __shared__ float T[64][65];
    int n0 = blockIdx.x * 64, k0 = blockIdx.y * 64;
    int c = threadIdx.x & 63, r0 = threadIdx.x >> 6;
#pragma unroll
    for (int i = 0; i < 16; i++) {
        int r = r0 + 4 * i;
        T[r][c] = W[(size_t)(k0 + r) * N + n0 + c];
    }
    __syncthreads();
    int ob = n0 >> 6;
    if (remap) { int p = ob / 12, h = ob % 12; ob = h * 3 + p; }
    size_t orow0 = (size_t)ob * 64;
#pragma unroll
    for (int i = 0; i < 16; i++) {
        int a = r0 + 4 * i;
        WT[(orow0 + a) * K + k0 + c] = f2bf(T[c][a]);
    }
}

// ---------------- checks: 26 gated record-sums
__global__ __launch_bounds__(256) void k_check(
    const float* __restrict__ records, const unsigned* __restrict__ lmask,
    const float* __restrict__ h, float* __restrict__ rec0, float* __restrict__ x24,
    float* __restrict__ x3, int layer) {
    int sd = blockIdx.x * 256 + threadIdx.x;
    if (sd >= SD) return;
    float acc[26];
#pragma unroll
    for (int j = 0; j < 26; j++) acc[j] = 0.f;
    const unsigned* lm = lmask + layer * (LL * NCC);
    int T = layer * NCC;
    for (int t = 0; t < T; t++) {
        float r = records[(size_t)t * SD + sd];
        unsigned m = lm[t];
#pragma unroll
        for (int j = 0; j < 26; j++)
            if (m & (1u << j)) acc[j] += r;
    }
    float hv = h[sd];
    rec0[sd] = hv - acc[0];
#pragma unroll
    for (int j = 0; j < 12; j++) x24[(size_t)j * SD + sd] = hv - acc[1 + j];
    x3[sd] = hv - acc[13];
#pragma unroll
    for (int j = 0; j < 12; j++) x24[(size_t)(12 + j) * SD + sd] = hv - acc[14 + j];
}

// ---------------- LayerNorm: wave per row; optional f32 and bf16 outputs
__global__ __launch_bounds__(64) void k_ln(const float* __restrict__ in, float* __restrict__ outf,
                                           u16* __restrict__ outb,
                                           const float* __restrict__ g, const float* __restrict__ b,
                                           int R) {
    int row = blockIdx.x;
    if (row >= R) return;
    int lane = threadIdx.x;
    const float* x = in + (size_t)row * DD;
    float vals[12];
    float s = 0.f;
#pragma unroll
    for (int i = 0; i < 12; i++) { vals[i] = x[lane + 64 * i]; s += vals[i]; }
#pragma unroll
    for (int m = 32; m >= 1; m >>= 1) s += __shfl_xor(s, m, 64);
    float mean = s * (1.f / DD);
    float vs = 0.f;
#pragma unroll
    for (int i = 0; i < 12; i++) { float d = vals[i] - mean; vs += d * d; }
#pragma unroll
    for (int m = 32; m >= 1; m >>= 1) vs += __shfl_xor(vs, m, 64);
    float rstd = rsqrtf(vs * (1.f / DD) + 1e-5f);
#pragma unroll
    for (int i = 0; i < 12; i++) {
        int d = lane + 64 * i;
        float y = (vals[i] - mean) * rstd * g[d] + b[d];
        if (outf) outf[(size_t)row * DD + d] = y;
        if (outb) outb[(size_t)row * DD + d] = f2bf(y);
    }
}

// ---------------- bf16 MFMA GEMM: C[z] = A[z] @ BT[z%zMod]^T (+bias), M=128
// A [128][lda] bf16, BT [N][ldbt] bf16 (row n = column n of B), C f32 or (mode1) gelu->bf16
__global__ __launch_bounds__(256) void k_mm(
    const u16* __restrict__ A, const u16* __restrict__ BT,
    const float* __restrict__ bias, void* __restrict__ Cv,
    int N, int K, int lda, int ldbt, int ldc,
    long long sA, long long sBT, long long sC, long long sBias,
    int zMod, int biasZmax, int mode) {
    __shared__ u16 As[128][40];
    __shared__ u16 Bs[64][40];
    int z = blockIdx.z;
    int zb = z % zMod;
    const u16* Ab = A + (size_t)z * sA;
    const u16* Bb = BT + (size_t)zb * sBT;
    int n0 = blockIdx.x * 64;
    int tid = threadIdx.x;
    int lane = tid & 63, wid = tid >> 6;
    int wm = (wid >> 1) * 64, wn = (wid & 1) * 32;
    int l15 = lane & 15, l4 = lane >> 4;
    int sr = tid >> 2, sseg = tid & 3;   // staging: 4 threads/row, 8 u16 each
    f32x4 acc[4][2];
#pragma unroll
    for (int i = 0; i < 4; i++) { acc[i][0] = (f32x4)0.f; acc[i][1] = (f32x4)0.f; }
    for (int k0 = 0; k0 < K; k0 += 32) {
        uint4 a0 = *(const uint4*)(Ab + (size_t)sr * lda + k0 + sseg * 8);
        uint4 a1 = *(const uint4*)(Ab + (size_t)(sr + 64) * lda + k0 + sseg * 8);
        uint4 bv = {0u, 0u, 0u, 0u};
        int n = n0 + sr;
        if (n < N) bv = *(const uint4*)(Bb + (size_t)n * ldbt + k0 + sseg * 8);
        *(uint4*)&As[sr][sseg * 8] = a0;
        *(uint4*)&As[sr + 64][sseg * 8] = a1;
        *(uint4*)&Bs[sr][sseg * 8] = bv;
        __syncthreads();
        short8 af[4], bfr[2];
#pragma unroll
        for (int i = 0; i < 4; i++) af[i] = *(const short8*)&As[wm + i * 16 + l15][l4 * 8];
#pragma unroll
        for (int j = 0; j < 2; j++) bfr[j] = *(const short8*)&Bs[wn + j * 16 + l15][l4 * 8];
#pragma unroll
        for (int i = 0; i < 4; i++)
#pragma unroll
            for (int j = 0; j < 2; j++)
                acc[i][j] = __builtin_amdgcn_mfma_f32_16x16x32_bf16(af[i], bfr[j], acc[i][j], 0, 0, 0);
        __syncthreads();
    }
    const float* bp = (bias != nullptr && z < biasZmax) ? bias + (size_t)zb * sBias : nullptr;
    if (mode == 0) {
        float* Cb = (float*)Cv + (size_t)z * sC;
#pragma unroll
        for (int i = 0; i < 4; i++) {
            int row = wm + i * 16 + l4 * 4;
#pragma unroll
            for (int j = 0; j < 2; j++) {
                int col = n0 + wn + j * 16 + l15;
                if (col >= N) continue;
                float bb = bp ? bp[col] : 0.f;
#pragma unroll
                for (int r = 0; r < 4; r++)
                    Cb[(size_t)(row + r) * ldc + col] = acc[i][j][r] + bb;
            }
        }
    } else {
        u16* Cb = (u16*)Cv + (size_t)z * sC;
#pragma unroll
        for (int i = 0; i < 4; i++) {
            int row = wm + i * 16 + l4 * 4;
#pragma unroll
            for (int j = 0; j < 2; j++) {
                int col = n0 + wn + j * 16 + l15;
                if (col >= N) continue;
                float bb = bp ? bp[col] : 0.f;
#pragma unroll
                for (int r = 0; r < 4; r++) {
                    float v = acc[i][j][r] + bb;
                    float c = v + 0.044715f * v * v * v;
                    float gv = 0.5f * v * (1.f + tanhf(0.7978845608028654f * c));
                    Cb[(size_t)(row + r) * ldc + col] = f2bf(gv);
                }
            }
        }
    }
}

// ---------------- fused causal attention on fused qkv [z][128][192] f32 -> ctx bf16 [z][128][64]
__global__ __launch_bounds__(256) void k_attn(const float* __restrict__ qkv,
                                              u16* __restrict__ ctx) {
    __shared__ float kv[SS * DHD];
    __shared__ float qs[16][DHD];
    __shared__ float sc[16][130];
    int z = blockIdx.y, s0 = blockIdx.x * 16;
    const float* base = qkv + (size_t)z * SS * 192;
    int tid = threadIdx.x;
    for (int idx = tid; idx < SS * DHD; idx += 256) {
        int t = idx >> 6, d = idx & 63;
        kv[idx] = base[t * 192 + 64 + d];
    }
    for (int idx = tid; idx < 16 * DHD; idx += 256) {
        int r = idx >> 6, d = idx & 63;
        qs[r][d] = base[(s0 + r) * 192 + d];
    }
    __syncthreads();
    int r = tid >> 4, tt = tid & 15;
    int s = s0 + r;
    float pl[8];
#pragma unroll
    for (int u = 0; u < 8; u++) {
        int t = tt + 16 * u;
        float dot;
        if (t <= s) {
            dot = 0.f;
            for (int d = 0; d < DHD; d++) dot += qs[r][d] * kv[t * DHD + d];
            dot *= 0.125f;
        } else {
            dot = -1e30f;
        }
        pl[u] = dot;
    }
    float mx = pl[0];
#pragma unroll
    for (int u = 1; u < 8; u++) mx = fmaxf(mx, pl[u]);
#pragma unroll
    for (int m = 1; m < 16; m <<= 1) mx = fmaxf(mx, __shfl_xor(mx, m, 16));
    float sum = 0.f;
#pragma unroll
    for (int u = 0; u < 8; u++) { pl[u] = __expf(pl[u] - mx); sum += pl[u]; }
#pragma unroll
    for (int m = 1; m < 16; m <<= 1) sum += __shfl_xor(sum, m, 16);
    float inv = 1.f / sum;
#pragma unroll
    for (int u = 0; u < 8; u++) sc[r][tt + 16 * u] = pl[u] * inv;
    __syncthreads();
    for (int idx = tid; idx < SS * DHD; idx += 256) {
        int t = idx >> 6, d = idx & 63;
        kv[idx] = base[t * 192 + 128 + d];
    }
    __syncthreads();
    int d = tid & 63, r0 = tid >> 6;
#pragma unroll
    for (int u = 0; u < 4; u++) {
        int rr = r0 + 4 * u;
        float a = 0.f;
        for (int t = 0; t < SS; t++) a += sc[rr][t] * kv[t * DHD + d];
        ctx[(size_t)z * SS * DHD + (size_t)(s0 + rr) * DHD + d] = f2bf(a);
    }
}

// ---------------- residual: copy head2 slots, resid = c1+sum(head2)+proj_b; slots 27/28
__global__ void k_resid(const float* __restrict__ tmp, const float* __restrict__ proj_b_i,
                        const float* __restrict__ mproj_b_i, float* __restrict__ reci,
                        float* __restrict__ resid) {
    int sd = blockIdx.x * 256 + threadIdx.x;
    if (sd >= SD) return;
    int d = sd % DD;
    float a = reci[sd];
#pragma unroll
    for (int j = 0; j < 12; j++) {
        float v = tmp[(size_t)j * SD + sd];
        reci[(size_t)(1 + j) * SD + sd] = v;
        a += v;
    }
    resid[sd] = a + proj_b_i[d];
    reci[(size_t)27 * SD + sd] = mproj_b_i[d];
    reci[(size_t)28 * SD + sd] = proj_b_i[d];
}

// ---------------- c5 = stream - c3 - sum(c4); h = resid + stream + mproj_b
__global__ void k_c5h(const float* __restrict__ reci, const float* __restrict__ strm,
                      const float* __restrict__ resid, const float* __restrict__ mproj_b_i,
                      float* __restrict__ slot26, float* __restrict__ h) {
    int sd = blockIdx.x * 256 + threadIdx.x;
    if (sd >= SD) return;
    int d = sd % DD;
    float s4 = 0.f;
#pragma unroll
    for (int j = 14; j <= 25; j++) s4 += reci[(size_t)j * SD + sd];
    float st = strm[sd];
    slot26[sd] = st - reci[(size_t)13 * SD + sd] - s4;
    h[sd] = resid[sd] + st + mproj_b_i[d];
}

extern "C" void kernel_launch(void* const* d_in, const int* in_sizes, int n_in,
                              void* d_out, int out_size, void* d_ws, size_t ws_size,
                              hipStream_t stream) {
    const int* ids = (const int*)d_in[0];
    const int* rm = (const int*)d_in[2];
    const float* wte = (const float*)d_in[3];
    const float* wpe = (const float*)d_in[4];
    const float* qkv_w = (const float*)d_in[5];
    const float* qkv_b = (const float*)d_in[6];
    const float* proj_w = (const float*)d_in[7];
    const float* proj_b = (const float*)d_in[8];
    const float* ln1_g = (const float*)d_in[9];
    const float* ln1_b = (const float*)d_in[10];
    const float* ln2_g = (const float*)d_in[11];
    const float* ln2_b = (const float*)d_in[12];
    const float* fc_w = (const float*)d_in[13];
    const float* fc_b = (const float*)d_in[14];
    const float* mproj_w = (const float*)d_in[15];
    const float* mproj_b = (const float*)d_in[16];
    const float* lnf_g = (const float*)d_in[17];
    const float* lnf_b = (const float*)d_in[18];
    float* out = (float*)d_out;

    float* ws = (float*)d_ws;
    size_t off = 0;
    float* records = ws + off; off += (size_t)LL * NCC * SD;
    float* x24  = ws + off; off += (size_t)24 * SD;
    float* tmp24= ws + off; off += (size_t)24 * SD;
    float* h    = ws + off; off += SD;
    float* x3   = ws + off; off += SD;
    float* resid= ws + off; off += SD;
    float* strm = ws + off; off += SD;
    float* qkvf = ws + off; off += (size_t)24 * SS * 192;
    float* qkvbp= ws + off; off += (size_t)LL * 3 * DD;
    u16* xlnb  = (u16*)(ws + off); off += (size_t)24 * SD / 2;
    u16* mlpAb = (u16*)(ws + off); off += (size_t)14 * SD / 2;
    u16* hfcb  = (u16*)(ws + off); off += (size_t)14 * SF / 2;
    u16* ctxb  = (u16*)(ws + off); off += (size_t)24 * SS * DHD / 2;
    u16* lnfb  = (u16*)(ws + off); off += SD / 2;
    u16* qkvhT = (u16*)(ws + off); off += (size_t)HH * 192 * DD / 2;
    u16* fcT   = (u16*)(ws + off); off += (size_t)FF * DD / 2;
    u16* mprojT= (u16*)(ws + off); off += (size_t)DD * FF / 2;
    u16* projT = (u16*)(ws + off); off += (size_t)DD * DD / 2;
    u16* wteb  = (u16*)(ws + off); off += (size_t)VV * DD / 2;
    unsigned* lmask = (unsigned*)(ws + off);

    k_masks<<<(LL * LL * NCC + 63) / 64, 64, 0, stream>>>(rm, lmask);
    k_embed<<<SD / 256, 256, 0, stream>>>(ids, wte, wpe, h);
    k_cvt<<<((VV * DD / 4) + 255) / 256, 256, 0, stream>>>(wte, wteb, VV * DD / 4);
    k_qkvb<<<(LL * 3 * DD + 255) / 256, 256, 0, stream>>>(qkv_b, qkvbp);

    for (int i = 0; i < LL; i++) {
        float* reci = records + (size_t)i * NCC * SD;
        const float* l1g = ln1_g + i * DD; const float* l1b = ln1_b + i * DD;
        const float* l2g = ln2_g + i * DD; const float* l2b = ln2_b + i * DD;

        // per-layer weight transpose-converts
        k_wt<<<dim3(36, 12), 256, 0, stream>>>(qkv_w + (size_t)i * DD * 3 * DD, qkvhT, DD, 3 * DD, 1);
        k_wt<<<dim3(48, 12), 256, 0, stream>>>(fc_w + (size_t)i * DD * FF, fcT, DD, FF, 0);
        k_wt<<<dim3(12, 48), 256, 0, stream>>>(mproj_w + (size_t)i * FF * DD, mprojT, FF, DD, 0);
        k_wt<<<dim3(12, 12), 256, 0, stream>>>(proj_w + (size_t)i * DD * DD, projT, DD, DD, 0);

        k_check<<<SD / 256, 256, 0, stream>>>(records, lmask, h, reci, x24, x3, i);

        // ln1 on x2||x4 (24 streams) -> bf16
        k_ln<<<24 * SS, 64, 0, stream>>>(x24, nullptr, xlnb, l1g, l1b, 24 * SS);
        // fused qkv per head, batch 24
        k_mm<<<dim3(3, 1, 24), 256, 0, stream>>>(
            xlnb, qkvhT, qkvbp + (size_t)i * 3 * DD, qkvf,
            192, DD, DD, DD, 192, SD, (long long)192 * DD, (long long)SS * 192, 192, 12, 24, 0);
        k_attn<<<dim3(SS / 16, 24), 256, 0, stream>>>(qkvf, ctxb);
        // ctx @ W_o per head, batch 24 -> tmp24 f32
        k_mm<<<dim3(12, 1, 24), 256, 0, stream>>>(
            ctxb, projT, nullptr, tmp24,
            DD, DHD, DHD, DD, DD, (long long)SS * DHD, 64, SD, 0, 12, 0, 0);
        k_resid<<<SD / 256, 256, 0, stream>>>(tmp24, proj_b + i * DD, mproj_b + i * DD, reci, resid);

        // MLP A-operands: z0=ln2(resid), z1=ln2(ln1(x3)), z2..13=ln2(head4)
        k_ln<<<SS, 64, 0, stream>>>(resid, nullptr, mlpAb, l2g, l2b, SS);
        k_ln<<<SS, 64, 0, stream>>>(x3, x3, nullptr, l1g, l1b, SS);
        k_ln<<<SS, 64, 0, stream>>>(x3, nullptr, mlpAb + SD, l2g, l2b, SS);
        k_ln<<<12 * SS, 64, 0, stream>>>(tmp24 + (size_t)12 * SD, nullptr, mlpAb + 2 * SD, l2g, l2b, 12 * SS);

        // fc GEMM batch 14, fused gelu -> bf16; bias only z=0 (stream)
        k_mm<<<dim3(48, 1, 14), 256, 0, stream>>>(
            mlpAb, fcT, fc_b + (size_t)i * FF, hfcb,
            FF, DD, DD, DD, FF, SD, 0, SF, 0, 1, 1, 1);
        // mproj batch 13 (c3 + 12 c4) -> records slots 13..25
        k_mm<<<dim3(12, 1, 13), 256, 0, stream>>>(
            hfcb + SF, mprojT, nullptr, reci + (size_t)13 * SD,
            DD, FF, FF, FF, DD, SF, 0, SD, 0, 1, 0, 0);
        // mproj stream -> strm
        k_mm<<<dim3(12, 1, 1), 256, 0, stream>>>(
            hfcb, mprojT, nullptr, strm,
            DD, FF, FF, FF, DD, 0, 0, 0, 0, 1, 0, 0);

        k_c5h<<<SD / 256, 256, 0, stream>>>(reci, strm, resid, mproj_b + i * DD,
                                            reci + (size_t)26 * SD, h);
    }

    // final LN + logits
    k_ln<<<SS, 64, 0, stream>>>(h, nullptr, lnfb, lnf_g, lnf_b, SS);
    k_mm<<<dim3((VV + 63) / 64, 1, 1), 256, 0, stream>>>(
        lnfb, wteb, nullptr, out,
        VV, DD, DD, DD, VV, 0, 0, 0, 0, 1, 0, 0);
}